// Round 1
// baseline (4508.582 us; speedup 1.0000x reference)
//
#include <hip/hip_runtime.h>

#define N_DB   100000
#define B_Q    1024
#define D_F    64
#define K_NN   100
#define NBINS  512
#define CAND_MAX 1024
#define JITTER 1e-6f
#define CT 128   // cols per dist block
#define RT 64    // rows per dist block

// ---------------- squared norms of db rows and query rows ----------------
__global__ __launch_bounds__(256) void k_sqnorm(
    const float* __restrict__ db_X, const float* __restrict__ input,
    float* __restrict__ d2, float* __restrict__ x2) {
    int wave = (blockIdx.x * blockDim.x + threadIdx.x) >> 6;
    int lane = threadIdx.x & 63;
    int total = N_DB + B_Q;
    if (wave >= total) return;
    const float* src = (wave < N_DB) ? (db_X + (size_t)wave * D_F)
                                     : (input + (size_t)(wave - N_DB) * D_F);
    float v = src[lane];
    float s = v * v;
    #pragma unroll
    for (int off = 32; off; off >>= 1) s += __shfl_xor(s, off, 64);
    if (lane == 0) {
        if (wave < N_DB) d2[wave] = s;
        else             x2[wave - N_DB] = s;
    }
}

// ---------------- distance tile: dist[r][n] = (x2 - 2 x.d + d2)/D ----------------
__global__ __launch_bounds__(256) void k_dist(
    const float* __restrict__ input, const float* __restrict__ db_X,
    const float* __restrict__ x2, const float* __restrict__ d2,
    float* __restrict__ dist, int b_base) {
    __shared__ float a_s[RT * D_F];      // [r][k]  16 KB
    __shared__ float b_s[16 * 516];      // [k4][c*4+e] padded, 33 KB
    int tid = threadIdx.x;
    int n0 = blockIdx.x * CT;
    int r0 = blockIdx.y * RT;            // chunk-local row base

    for (int f = tid; f < RT * D_F / 4; f += 256) {       // 1024 float4
        int r = f >> 4, q = f & 15;
        float4 w = *(const float4*)(input + (size_t)(b_base + r0 + r) * D_F + q * 4);
        *(float4*)(a_s + r * D_F + q * 4) = w;
    }
    for (int f = tid; f < CT * D_F / 4; f += 256) {       // 2048 float4
        int c = f >> 4, q = f & 15;
        int n = n0 + c;
        float4 w = make_float4(0.f, 0.f, 0.f, 0.f);
        if (n < N_DB) w = *(const float4*)(db_X + (size_t)n * D_F + q * 4);
        *(float4*)(b_s + q * 516 + c * 4) = w;
    }
    __syncthreads();

    int cg = tid & 31, rg = tid >> 5;    // 32 col-groups x 8 row-groups
    float acc[8][4];
    #pragma unroll
    for (int i = 0; i < 8; i++)
        #pragma unroll
        for (int j = 0; j < 4; j++) acc[i][j] = 0.f;

    #pragma unroll
    for (int k4 = 0; k4 < 16; k4++) {
        float4 av[8], bv[4];
        #pragma unroll
        for (int i = 0; i < 8; i++)
            av[i] = *(const float4*)(a_s + (rg * 8 + i) * D_F + k4 * 4);
        #pragma unroll
        for (int j = 0; j < 4; j++)
            bv[j] = *(const float4*)(b_s + k4 * 516 + (cg + 32 * j) * 4);
        #pragma unroll
        for (int i = 0; i < 8; i++)
            #pragma unroll
            for (int j = 0; j < 4; j++)
                acc[i][j] += av[i].x * bv[j].x + av[i].y * bv[j].y
                           + av[i].z * bv[j].z + av[i].w * bv[j].w;
    }

    const float inv_d = 1.0f / D_F;
    #pragma unroll
    for (int i = 0; i < 8; i++) {
        int r = r0 + rg * 8 + i;
        float xx = x2[b_base + r];
        #pragma unroll
        for (int j = 0; j < 4; j++) {
            int n = n0 + cg + 32 * j;
            if (n < N_DB)
                dist[(size_t)r * N_DB + n] = (xx - 2.0f * acc[i][j] + d2[n]) * inv_d;
        }
    }
}

// ---------------- per-row top-K: histogram threshold + exact rank select ----------------
__global__ __launch_bounds__(256) void k_select(
    const float* __restrict__ dist, int* __restrict__ idx, int b_base) {
    int r = blockIdx.x;                  // chunk-local row
    int b = b_base + r;
    const float* drow = dist + (size_t)r * N_DB;
    __shared__ int hist[NBINS];
    __shared__ int s_tbin, s_cnt;
    __shared__ uint2 cand[CAND_MAX];
    int tid = threadIdx.x;

    for (int i = tid; i < NBINS; i += 256) hist[i] = 0;
    if (tid == 0) s_cnt = 0;
    __syncthreads();

    for (int n = tid; n < N_DB; n += 256) {
        float d = drow[n];
        int bin = (int)(d * 256.0f);
        bin = bin < 0 ? 0 : (bin > NBINS - 1 ? NBINS - 1 : bin);
        atomicAdd(&hist[bin], 1);
    }
    __syncthreads();

    if (tid == 0) {
        int cum = 0, t = NBINS - 1;
        for (int i = 0; i < NBINS; i++) {
            cum += hist[i];
            if (cum >= K_NN) { t = i; break; }
        }
        s_tbin = t;
    }
    __syncthreads();
    int tbin = s_tbin;

    for (int n = tid; n < N_DB; n += 256) {
        float d = drow[n];
        int bin = (int)(d * 256.0f);
        bin = bin < 0 ? 0 : (bin > NBINS - 1 ? NBINS - 1 : bin);
        if (bin <= tbin) {
            int pos = atomicAdd(&s_cnt, 1);
            if (pos < CAND_MAX) cand[pos] = make_uint2(__float_as_uint(d), (unsigned)n);
        }
    }
    __syncthreads();

    int cnt = s_cnt; if (cnt > CAND_MAX) cnt = CAND_MAX;
    for (int i = tid; i < cnt; i += 256) {
        unsigned ki = cand[i].x;
        int rank = 0;
        for (int j = 0; j < cnt; j++) {
            unsigned kj = cand[j].x;
            rank += (kj < ki) || (kj == ki && j < i);
        }
        if (rank < K_NN) idx[(size_t)b * K_NN + rank] = (int)cand[i].y;
    }
}

// ---------------- per-row regression + loss accumulate ----------------
__global__ __launch_bounds__(256) void k_regress(
    const float* __restrict__ input, const float* __restrict__ target,
    const float* __restrict__ db_X, const float* __restrict__ db_y,
    const int* __restrict__ idx, float* __restrict__ out) {
    int b = blockIdx.x;
    int tid = threadIdx.x;
    __shared__ float A[K_NN][D_F + 2];        // [100][66], col0 = 1
    __shared__ float M[D_F + 1][D_F + 2];     // [65][66]
    __shared__ float v[D_F + 1];
    __shared__ float xa[D_F + 1];
    __shared__ float yv[K_NN];
    __shared__ int nbr[K_NN];

    if (tid < K_NN) nbr[tid] = idx[(size_t)b * K_NN + tid];
    if (tid < D_F) xa[1 + tid] = input[(size_t)b * D_F + tid];
    if (tid == 0) xa[0] = 1.0f;
    __syncthreads();

    for (int f = tid; f < K_NN * (D_F / 4); f += 256) {   // 1600
        int k = f >> 4, q = f & 15;
        float4 w = *(const float4*)(db_X + (size_t)nbr[k] * D_F + q * 4);
        A[k][1 + q * 4 + 0] = w.x;
        A[k][1 + q * 4 + 1] = w.y;
        A[k][1 + q * 4 + 2] = w.z;
        A[k][1 + q * 4 + 3] = w.w;
    }
    if (tid < K_NN) { A[tid][0] = 1.0f; yv[tid] = db_y[nbr[tid]]; }
    __syncthreads();

    // AtA + jitter
    for (int c = tid; c < (D_F + 1) * (D_F + 1); c += 256) {
        int p = c / (D_F + 1), q = c % (D_F + 1);
        float acc = (p == q) ? JITTER : 0.0f;
        for (int k = 0; k < K_NN; k++) acc += A[k][p] * A[k][q];
        M[p][q] = acc;
    }
    // Aty
    for (int p = tid; p < D_F + 1; p += 256) {
        float acc = 0.f;
        for (int k = 0; k < K_NN; k++) acc += A[k][p] * yv[k];
        v[p] = acc;
    }
    __syncthreads();

    // Gaussian elimination (SPD + jitter, no pivoting). Row j / col j frozen at step j.
    for (int j = 0; j < D_F + 1; j++) {
        float inv = 1.0f / M[j][j];
        int rem = D_F - j;                    // rows/cols j+1..64
        for (int c = tid; c < rem * rem; c += 256) {
            int i = j + 1 + c / rem, k = j + 1 + c % rem;
            M[i][k] -= M[i][j] * M[j][k] * inv;
        }
        __syncthreads();
    }
    // forward: v[i] -= l_ij * v[j],  l_ij = M[i][j]/M[j][j]
    for (int j = 0; j < D_F + 1; j++) {
        float inv = 1.0f / M[j][j];
        float vj = v[j];
        for (int i = j + 1 + tid; i < D_F + 1; i += 256)
            v[i] -= M[i][j] * inv * vj;
        __syncthreads();
    }
    // back: x[j] = v[j]/U[j][j]; v[i] -= U[i][j]*x[j] (i<j)
    for (int j = D_F; j >= 0; j--) {
        if (tid == 0) v[j] /= M[j][j];
        __syncthreads();
        float xj = v[j];
        for (int i = tid; i < j; i += 256) v[i] -= M[i][j] * xj;
        __syncthreads();
    }

    if (tid == 0) {
        float pred = 0.f;
        for (int q = 0; q <= D_F; q++) pred += xa[q] * v[q];
        float e = pred - target[b];
        atomicAdd(out, e * e * (1.0f / B_Q));
    }
}

extern "C" void kernel_launch(void* const* d_in, const int* in_sizes, int n_in,
                              void* d_out, int out_size, void* d_ws, size_t ws_size,
                              hipStream_t stream) {
    const float* input  = (const float*)d_in[0];
    const float* target = (const float*)d_in[1];
    const float* db_X   = (const float*)d_in[2];
    const float* db_y   = (const float*)d_in[3];
    float* out = (float*)d_out;

    char* ws = (char*)d_ws;
    size_t off = 0;
    auto alloc = [&](size_t bytes) {
        size_t o = off;
        off += (bytes + 255) & ~(size_t)255;
        return o;
    };
    size_t o_d2  = alloc((size_t)N_DB * 4);
    size_t o_x2  = alloc((size_t)B_Q * 4);
    size_t o_idx = alloc((size_t)B_Q * K_NN * 4);
    size_t fixed = off;

    int CB = 256;                         // rows per chunk (cache-friendly cap)
    while (CB > 64 && fixed + (size_t)CB * N_DB * 4 > ws_size) CB >>= 1;
    size_t o_dist = alloc((size_t)CB * N_DB * 4);

    float* d2   = (float*)(ws + o_d2);
    float* x2   = (float*)(ws + o_x2);
    int*   idx  = (int*)(ws + o_idx);
    float* dist = (float*)(ws + o_dist);

    hipMemsetAsync(d_out, 0, sizeof(float) * out_size, stream);

    {
        int waves  = N_DB + B_Q;
        int blocks = (waves + 3) / 4;     // 4 waves per 256-thread block
        k_sqnorm<<<blocks, 256, 0, stream>>>(db_X, input, d2, x2);
    }

    for (int b0 = 0; b0 < B_Q; b0 += CB) {
        dim3 g((N_DB + CT - 1) / CT, CB / RT);
        k_dist<<<g, 256, 0, stream>>>(input, db_X, x2, d2, dist, b0);
        k_select<<<CB, 256, 0, stream>>>(dist, idx, b0);
    }

    k_regress<<<B_Q, 256, 0, stream>>>(input, target, db_X, db_y, idx, out);
}

// Round 2
// 566.102 us; speedup vs baseline: 7.9643x; 7.9643x over previous
//
#include <hip/hip_runtime.h>

#define N_DB   100000
#define B_Q    1024
#define D_F    64
#define K_NN   100
#define JITTER 1e-6f
#define CMAX   512
#define TP     80    // padded LDS k-stride (bf16 elems) -> 160 B rows, ~4-way banks
#define AST    68    // k_regress LDS row stride (f32), 16B-aligned float4 tiles

typedef __attribute__((ext_vector_type(8))) short bf16x8;
typedef __attribute__((ext_vector_type(4))) float f32x4;

__device__ __forceinline__ unsigned short f2b(float x) {   // f32 -> bf16 RNE
    unsigned u = __float_as_uint(x);
    u += 0x7FFF + ((u >> 16) & 1);
    return (unsigned short)(u >> 16);
}

// ---------------- squared norms ----------------
__global__ __launch_bounds__(256) void k_sqnorm(
    const float* __restrict__ db_X, const float* __restrict__ input,
    float* __restrict__ d2, float* __restrict__ x2) {
    int wave = (blockIdx.x * blockDim.x + threadIdx.x) >> 6;
    int lane = threadIdx.x & 63;
    if (wave >= N_DB + B_Q) return;
    const float* src = (wave < N_DB) ? (db_X + (size_t)wave * D_F)
                                     : (input + (size_t)(wave - N_DB) * D_F);
    float v = src[lane];
    float s = v * v;
    #pragma unroll
    for (int off = 32; off; off >>= 1) s += __shfl_xor(s, off, 64);
    if (lane == 0) {
        if (wave < N_DB) d2[wave] = s;
        else             x2[wave - N_DB] = s;
    }
}

// ---------------- bf16 MFMA GEMM -> byte bins ----------------
// 128x128 tile, 4 waves (2x2), each wave 64x64 via 4x4 frags of 16x16x32.
__global__ __launch_bounds__(256) void k_gemm_bin(
    const float* __restrict__ input, const float* __restrict__ db_X,
    const float* __restrict__ x2, const float* __restrict__ d2,
    unsigned char* __restrict__ binb) {
    __shared__ unsigned short As[128 * TP];
    __shared__ unsigned short Bs[128 * TP];
    __shared__ float x2s[128], d2s[128];
    int tid = threadIdx.x;
    int n0 = blockIdx.x * 128;
    int b0 = blockIdx.y * 128;

    #pragma unroll
    for (int it = 0; it < 8; it++) {                     // A: 2048 float4
        int f = it * 256 + tid;
        int r = f >> 4, k4 = f & 15;
        float4 w = *(const float4*)(input + (size_t)(b0 + r) * D_F + k4 * 4);
        uint2 p;
        p.x = (unsigned)f2b(w.x) | ((unsigned)f2b(w.y) << 16);
        p.y = (unsigned)f2b(w.z) | ((unsigned)f2b(w.w) << 16);
        *(uint2*)(&As[r * TP + k4 * 4]) = p;
    }
    #pragma unroll
    for (int it = 0; it < 8; it++) {                     // B: db rows
        int f = it * 256 + tid;
        int c = f >> 4, k4 = f & 15;
        int n = n0 + c;
        float4 w = make_float4(0.f, 0.f, 0.f, 0.f);
        if (n < N_DB) w = *(const float4*)(db_X + (size_t)n * D_F + k4 * 4);
        uint2 p;
        p.x = (unsigned)f2b(w.x) | ((unsigned)f2b(w.y) << 16);
        p.y = (unsigned)f2b(w.z) | ((unsigned)f2b(w.w) << 16);
        *(uint2*)(&Bs[c * TP + k4 * 4]) = p;
    }
    if (tid < 128) {
        x2s[tid] = x2[b0 + tid];
        int n = n0 + tid;
        d2s[tid] = (n < N_DB) ? d2[n] : 0.f;
    }
    __syncthreads();

    int lane = tid & 63, wid = tid >> 6;
    int wr = (wid >> 1) * 64, wc = (wid & 1) * 64;
    int fr = lane & 15, fq = lane >> 4;

    f32x4 acc[4][4];
    #pragma unroll
    for (int i = 0; i < 4; i++)
        #pragma unroll
        for (int j = 0; j < 4; j++)
            acc[i][j] = (f32x4){0.f, 0.f, 0.f, 0.f};

    #pragma unroll
    for (int ks = 0; ks < 2; ks++) {
        int koff = fq * 8 + ks * 32;
        bf16x8 a[4], b[4];
        #pragma unroll
        for (int i = 0; i < 4; i++)
            a[i] = *(const bf16x8*)(&As[(wr + i * 16 + fr) * TP + koff]);
        #pragma unroll
        for (int j = 0; j < 4; j++)
            b[j] = *(const bf16x8*)(&Bs[(wc + j * 16 + fr) * TP + koff]);
        #pragma unroll
        for (int i = 0; i < 4; i++)
            #pragma unroll
            for (int j = 0; j < 4; j++)
                acc[i][j] = __builtin_amdgcn_mfma_f32_16x16x32_bf16(a[i], b[j], acc[i][j], 0, 0, 0);
    }

    const float inv_d = 1.0f / D_F;
    #pragma unroll
    for (int i = 0; i < 4; i++) {
        #pragma unroll
        for (int r = 0; r < 4; r++) {
            int row = wr + i * 16 + fq * 4 + r;          // C/D: col=lane&15, row=(lane>>4)*4+reg
            float xx = x2s[row];
            size_t rowbase = (size_t)(b0 + row) * N_DB;
            #pragma unroll
            for (int j = 0; j < 4; j++) {
                int col = wc + j * 16 + fr;
                int n = n0 + col;
                if (n < N_DB) {
                    float dv = (xx + d2s[col] - 2.0f * acc[i][j][r]) * inv_d;
                    int bin = (int)(dv * 64.0f);
                    bin = bin < 0 ? 0 : (bin > 255 ? 255 : bin);
                    binb[rowbase + n] = (unsigned char)bin;
                }
            }
        }
    }
}

// ---------------- per-row selection from byte bins ----------------
// coarse(16)+fine(16) register counting -> threshold; collect <= thr+2;
// exact f32 refine of candidates; exact rank -> top-100 set.
__global__ __launch_bounds__(256) void k_select(
    const unsigned char* __restrict__ binb, const float* __restrict__ input,
    const float* __restrict__ db_X, const float* __restrict__ x2,
    const float* __restrict__ d2, int* __restrict__ idx) {
    int b = blockIdx.x, tid = threadIdx.x;
    int lane = tid & 63;
    __shared__ float xrow[64];
    __shared__ int h[16];
    __shared__ int s_coarse, s_base, s_thr, s_cnt;
    __shared__ int cand_n[CMAX];
    __shared__ float cand_d[CMAX];

    if (tid < 64) xrow[tid] = input[(size_t)b * 64 + tid];
    if (tid < 16) h[tid] = 0;
    if (tid == 0) s_cnt = 0;
    __syncthreads();

    const uint4* row4 = (const uint4*)(binb + (size_t)b * N_DB);  // 6250 uint4

    // pass 1: coarse counts (by >> 4)
    int c16[16];
    #pragma unroll
    for (int j = 0; j < 16; j++) c16[j] = 0;
    for (int it = 0; it < 25; it++) {
        int v = it * 256 + tid;
        if (v < 6250) {
            uint4 w = row4[v];
            unsigned ws[4] = {w.x, w.y, w.z, w.w};
            #pragma unroll
            for (int q = 0; q < 4; q++) {
                #pragma unroll
                for (int e = 0; e < 4; e++) {
                    int cb = (int)((ws[q] >> (8 * e)) & 255u) >> 4;
                    #pragma unroll
                    for (int j = 0; j < 16; j++) c16[j] += (cb == j);
                }
            }
        }
    }
    #pragma unroll
    for (int j = 0; j < 16; j++) {
        int s = c16[j];
        #pragma unroll
        for (int off = 32; off; off >>= 1) s += __shfl_xor(s, off, 64);
        if (lane == 0) atomicAdd(&h[j], s);
    }
    __syncthreads();
    if (tid == 0) {
        int cum = 0, C = 15, base = 0;
        for (int j = 0; j < 16; j++) {
            if (cum + h[j] >= K_NN) { C = j; base = cum; break; }
            cum += h[j];
        }
        s_coarse = C; s_base = base;
    }
    __syncthreads();
    int C = s_coarse, base = s_base;
    if (tid < 16) h[tid] = 0;
    __syncthreads();

    // pass 2: fine counts within coarse bin C
    #pragma unroll
    for (int j = 0; j < 16; j++) c16[j] = 0;
    for (int it = 0; it < 25; it++) {
        int v = it * 256 + tid;
        if (v < 6250) {
            uint4 w = row4[v];
            unsigned ws[4] = {w.x, w.y, w.z, w.w};
            #pragma unroll
            for (int q = 0; q < 4; q++) {
                #pragma unroll
                for (int e = 0; e < 4; e++) {
                    int by = (int)((ws[q] >> (8 * e)) & 255u);
                    #pragma unroll
                    for (int j = 0; j < 16; j++) c16[j] += (by == C * 16 + j);
                }
            }
        }
    }
    #pragma unroll
    for (int j = 0; j < 16; j++) {
        int s = c16[j];
        #pragma unroll
        for (int off = 32; off; off >>= 1) s += __shfl_xor(s, off, 64);
        if (lane == 0) atomicAdd(&h[j], s);
    }
    __syncthreads();
    if (tid == 0) {
        int cum = base, t = C * 16 + 15;
        for (int j = 0; j < 16; j++) {
            cum += h[j];
            if (cum >= K_NN) { t = C * 16 + j; break; }
        }
        int thr = t + 2;                          // margin for bf16 GEMM error
        s_thr = thr > 255 ? 255 : thr;
    }
    __syncthreads();
    int thr = s_thr;

    // pass 3: collect candidates
    for (int it = 0; it < 25; it++) {
        int v = it * 256 + tid;
        if (v < 6250) {
            uint4 w = row4[v];
            unsigned ws[4] = {w.x, w.y, w.z, w.w};
            #pragma unroll
            for (int q = 0; q < 4; q++) {
                #pragma unroll
                for (int e = 0; e < 4; e++) {
                    int by = (int)((ws[q] >> (8 * e)) & 255u);
                    if (by <= thr) {
                        int pos = atomicAdd(&s_cnt, 1);
                        if (pos < CMAX) cand_n[pos] = v * 16 + q * 4 + e;
                    }
                }
            }
        }
    }
    __syncthreads();
    int cnt = s_cnt; if (cnt > CMAX) cnt = CMAX;

    // exact f32 refine
    float xx = x2[b];
    for (int c = tid; c < cnt; c += 256) {
        int n = cand_n[c];
        const float* dr = db_X + (size_t)n * D_F;
        float dot = 0.f;
        #pragma unroll
        for (int k = 0; k < D_F; k++) dot += xrow[k] * dr[k];
        cand_d[c] = (xx - 2.0f * dot + d2[n]) * (1.0f / D_F);
    }
    __syncthreads();

    // exact rank over candidates (total order via (dist, idx))
    for (int c = tid; c < cnt; c += 256) {
        float dc = cand_d[c]; int nc = cand_n[c];
        int rank = 0;
        for (int j = 0; j < cnt; j++) {
            float dj = cand_d[j];
            rank += (dj < dc) || (dj == dc && cand_n[j] < nc);
        }
        if (rank < K_NN) idx[(size_t)b * K_NN + rank] = nc;
    }
}

// ---------------- per-row regression + loss ----------------
__global__ __launch_bounds__(256) void k_regress(
    const float* __restrict__ input, const float* __restrict__ target,
    const float* __restrict__ db_X, const float* __restrict__ db_y,
    const int* __restrict__ idx, float* __restrict__ out) {
    int b = blockIdx.x, tid = threadIdx.x;
    __shared__ float A[K_NN * AST];          // [k][p], col0 = 1, cols 65..67 = 0
    __shared__ float M[65 * AST];
    __shared__ float v[65], xa[68], yv[K_NN];
    __shared__ int nbr[K_NN];

    if (tid < K_NN) {
        int n = idx[(size_t)b * K_NN + tid];
        nbr[tid] = n;
        yv[tid] = db_y[n];
    }
    if (tid < 64) xa[1 + tid] = input[(size_t)b * D_F + tid];
    if (tid == 0) { xa[0] = 1.f; xa[65] = xa[66] = xa[67] = 0.f; }
    __syncthreads();

    for (int f = tid; f < K_NN * AST; f += 256) {
        int k = f / AST, c = f - k * AST;
        float val = 0.f;
        if (c == 0) val = 1.f;
        else if (c <= 64) val = db_X[(size_t)nbr[k] * D_F + (c - 1)];
        A[f] = val;
    }
    __syncthreads();

    // AtA via 4x4 register tiles (17x17 tiles over 65x65+pad)
    for (int t = tid; t < 289; t += 256) {
        int ti = t / 17, tj = t % 17;
        int p0 = ti * 4, q0 = tj * 4;
        float acc[4][4];
        #pragma unroll
        for (int ii = 0; ii < 4; ii++)
            #pragma unroll
            for (int jj = 0; jj < 4; jj++) acc[ii][jj] = 0.f;
        for (int k = 0; k < K_NN; k++) {
            float4 ap = *(const float4*)(&A[k * AST + p0]);
            float4 aq = *(const float4*)(&A[k * AST + q0]);
            float app[4] = {ap.x, ap.y, ap.z, ap.w};
            float aqq[4] = {aq.x, aq.y, aq.z, aq.w};
            #pragma unroll
            for (int ii = 0; ii < 4; ii++)
                #pragma unroll
                for (int jj = 0; jj < 4; jj++) acc[ii][jj] += app[ii] * aqq[jj];
        }
        #pragma unroll
        for (int ii = 0; ii < 4; ii++)
            #pragma unroll
            for (int jj = 0; jj < 4; jj++) {
                int p = p0 + ii, q = q0 + jj;
                if (p < 65 && q < 65)
                    M[p * AST + q] = acc[ii][jj] + (p == q ? JITTER : 0.f);
            }
    }
    for (int p = tid; p < 65; p += 256) {
        float s = 0.f;
        for (int k = 0; k < K_NN; k++) s += A[k * AST + p] * yv[k];
        v[p] = s;
    }
    __syncthreads();

    // Gaussian elimination (SPD, no pivot); cols >= j+1 updated, col j frozen.
    for (int j = 0; j < 65; j++) {
        float inv = 1.0f / M[j * AST + j];
        int kcol = j + 1 + (tid & 63);
        int rbase = j + 1 + (tid >> 6);
        if (kcol <= 64) {
            float mjk = M[j * AST + kcol] * inv;
            for (int i = rbase; i <= 64; i += 4)
                M[i * AST + kcol] -= M[i * AST + j] * mjk;
        }
        __syncthreads();
    }
    // forward solve
    for (int j = 0; j < 65; j++) {
        float inv = 1.0f / M[j * AST + j];
        float vj = v[j];
        for (int i = j + 1 + tid; i < 65; i += 256) v[i] -= M[i * AST + j] * inv * vj;
        __syncthreads();
    }
    // back substitution
    for (int j = 64; j >= 0; j--) {
        if (tid == 0) v[j] /= M[j * AST + j];
        __syncthreads();
        float xj = v[j];
        for (int i = tid; i < j; i += 256) v[i] -= M[i * AST + j] * xj;
        __syncthreads();
    }

    if (tid == 0) {
        float pred = 0.f;
        for (int q = 0; q <= 64; q++) pred += xa[q] * v[q];
        float e = pred - target[b];
        atomicAdd(out, e * e * (1.0f / B_Q));
    }
}

extern "C" void kernel_launch(void* const* d_in, const int* in_sizes, int n_in,
                              void* d_out, int out_size, void* d_ws, size_t ws_size,
                              hipStream_t stream) {
    const float* input  = (const float*)d_in[0];
    const float* target = (const float*)d_in[1];
    const float* db_X   = (const float*)d_in[2];
    const float* db_y   = (const float*)d_in[3];
    float* out = (float*)d_out;

    char* ws = (char*)d_ws;
    size_t off = 0;
    auto alloc = [&](size_t bytes) {
        size_t o = off;
        off += (bytes + 255) & ~(size_t)255;
        return o;
    };
    float* d2   = (float*)(ws + alloc((size_t)N_DB * 4));
    float* x2   = (float*)(ws + alloc((size_t)B_Q * 4));
    int*   idx  = (int*)(ws + alloc((size_t)B_Q * K_NN * 4));
    unsigned char* binb = (unsigned char*)(ws + alloc((size_t)B_Q * N_DB));

    hipMemsetAsync(d_out, 0, sizeof(float) * out_size, stream);

    {
        int waves = N_DB + B_Q;
        k_sqnorm<<<(waves + 3) / 4, 256, 0, stream>>>(db_X, input, d2, x2);
    }
    {
        dim3 g((N_DB + 127) / 128, B_Q / 128);
        k_gemm_bin<<<g, 256, 0, stream>>>(input, db_X, x2, d2, binb);
    }
    k_select<<<B_Q, 256, 0, stream>>>(binb, input, db_X, x2, d2, idx);
    k_regress<<<B_Q, 256, 0, stream>>>(input, target, db_X, db_y, idx, out);
}

// Round 3
// 470.784 us; speedup vs baseline: 9.5768x; 1.2025x over previous
//
#include <hip/hip_runtime.h>

#define N_DB   100000
#define B_Q    1024
#define D_F    64
#define K_NN   100
#define JITTER 1e-6f
#define CMAX   3072
#define STGT   40    // sample cumulative target (~1/8 sampling -> ~320 full-row cands)
#define TP     80    // padded LDS k-stride (bf16 elems)
#define AST    68    // k_regress LDS row stride (f32)

typedef __attribute__((ext_vector_type(8))) short bf16x8;
typedef __attribute__((ext_vector_type(4))) float f32x4;

__device__ __forceinline__ unsigned short f2b(float x) {   // f32 -> bf16 RNE
    unsigned u = __float_as_uint(x);
    u += 0x7FFF + ((u >> 16) & 1);
    return (unsigned short)(u >> 16);
}

// ---------------- squared norms ----------------
__global__ __launch_bounds__(256) void k_sqnorm(
    const float* __restrict__ db_X, const float* __restrict__ input,
    float* __restrict__ d2, float* __restrict__ x2) {
    int wave = (blockIdx.x * blockDim.x + threadIdx.x) >> 6;
    int lane = threadIdx.x & 63;
    if (wave >= N_DB + B_Q) return;
    const float* src = (wave < N_DB) ? (db_X + (size_t)wave * D_F)
                                     : (input + (size_t)(wave - N_DB) * D_F);
    float v = src[lane];
    float s = v * v;
    #pragma unroll
    for (int off = 32; off; off >>= 1) s += __shfl_xor(s, off, 64);
    if (lane == 0) {
        if (wave < N_DB) d2[wave] = s;
        else             x2[wave - N_DB] = s;
    }
}

// ---------------- bf16 MFMA GEMM -> byte bins (coalesced u32 stores) ----------------
__global__ __launch_bounds__(256) void k_gemm_bin(
    const float* __restrict__ input, const float* __restrict__ db_X,
    const float* __restrict__ x2, const float* __restrict__ d2,
    unsigned char* __restrict__ binb) {
    __shared__ unsigned short As[128 * TP];
    __shared__ unsigned short Bs[128 * TP];
    __shared__ float x2s[128], d2s[128];
    int tid = threadIdx.x;
    int n0 = blockIdx.x * 128;
    int b0 = blockIdx.y * 128;

    #pragma unroll
    for (int it = 0; it < 8; it++) {                     // A: 2048 float4
        int f = it * 256 + tid;
        int r = f >> 4, k4 = f & 15;
        float4 w = *(const float4*)(input + (size_t)(b0 + r) * D_F + k4 * 4);
        uint2 p;
        p.x = (unsigned)f2b(w.x) | ((unsigned)f2b(w.y) << 16);
        p.y = (unsigned)f2b(w.z) | ((unsigned)f2b(w.w) << 16);
        *(uint2*)(&As[r * TP + k4 * 4]) = p;
    }
    #pragma unroll
    for (int it = 0; it < 8; it++) {                     // B: db rows
        int f = it * 256 + tid;
        int c = f >> 4, k4 = f & 15;
        int n = n0 + c;
        float4 w = make_float4(0.f, 0.f, 0.f, 0.f);
        if (n < N_DB) w = *(const float4*)(db_X + (size_t)n * D_F + k4 * 4);
        uint2 p;
        p.x = (unsigned)f2b(w.x) | ((unsigned)f2b(w.y) << 16);
        p.y = (unsigned)f2b(w.z) | ((unsigned)f2b(w.w) << 16);
        *(uint2*)(&Bs[c * TP + k4 * 4]) = p;
    }
    if (tid < 128) {
        x2s[tid] = x2[b0 + tid];
        int n = n0 + tid;
        d2s[tid] = (n < N_DB) ? d2[n] : 0.f;
    }
    __syncthreads();

    int lane = tid & 63, wid = tid >> 6;
    int wr = (wid >> 1) * 64, wc = (wid & 1) * 64;
    int fr = lane & 15, fq = lane >> 4;

    f32x4 acc[4][4];
    #pragma unroll
    for (int i = 0; i < 4; i++)
        #pragma unroll
        for (int j = 0; j < 4; j++)
            acc[i][j] = (f32x4){0.f, 0.f, 0.f, 0.f};

    #pragma unroll
    for (int ks = 0; ks < 2; ks++) {
        int koff = fq * 8 + ks * 32;
        bf16x8 a[4], b[4];
        #pragma unroll
        for (int i = 0; i < 4; i++)
            a[i] = *(const bf16x8*)(&As[(wr + i * 16 + fr) * TP + koff]);
        #pragma unroll
        for (int j = 0; j < 4; j++)
            b[j] = *(const bf16x8*)(&Bs[(wc + j * 16 + fr) * TP + koff]);
        #pragma unroll
        for (int i = 0; i < 4; i++)
            #pragma unroll
            for (int j = 0; j < 4; j++)
                acc[i][j] = __builtin_amdgcn_mfma_f32_16x16x32_bf16(a[i], b[j], acc[i][j], 0, 0, 0);
    }

    // epilogue: bin -> shfl-transpose so each lane stores 4 CONSECUTIVE cols as u32
    const float inv_d = 1.0f / D_F;
    int jsel = fr >> 2;
    int base_src = (fq << 4) | (4 * (fr & 3));
    #pragma unroll
    for (int i = 0; i < 4; i++) {
        #pragma unroll
        for (int r = 0; r < 4; r++) {
            int row = wr + i * 16 + fq * 4 + r;          // C/D: col=lane&15, row=(lane>>4)*4+reg
            float xx = x2s[row];
            unsigned p = 0;
            #pragma unroll
            for (int j = 0; j < 4; j++) {
                int col = wc + j * 16 + fr;
                float dv = (xx + d2s[col] - 2.0f * acc[i][j][r]) * inv_d;
                int bin = (int)(dv * 64.0f);
                bin = bin < 0 ? 0 : (bin > 255 ? 255 : bin);
                p |= (unsigned)bin << (8 * j);
            }
            unsigned out = 0;
            #pragma unroll
            for (int e = 0; e < 4; e++) {
                unsigned q = __shfl(p, base_src + e, 64);
                out |= ((q >> (8 * jsel)) & 255u) << (8 * e);
            }
            int ncol = n0 + wc + 4 * fr;                 // 4 consecutive cols per lane
            if (ncol + 3 < N_DB)
                *(unsigned*)(binb + (size_t)(b0 + row) * N_DB + ncol) = out;
        }
    }
}

// ---------------- per-row selection: sampled threshold + 1 verify/collect pass ----------------
__global__ __launch_bounds__(256) void k_select(
    const unsigned char* __restrict__ binb, const float* __restrict__ input,
    const float* __restrict__ db_X, const float* __restrict__ x2,
    const float* __restrict__ d2, int* __restrict__ idx) {
    int b = blockIdx.x, tid = threadIdx.x, lane = tid & 63;
    __shared__ float xrow[64];
    __shared__ int hist[256];
    __shared__ int s_thr, s_cnt, s_nle;
    __shared__ int cand_n[CMAX];
    __shared__ float cand_d[CMAX];

    if (tid < 64) xrow[tid] = input[(size_t)b * 64 + tid];
    hist[tid] = 0; if (tid < 256 - 256) {}               // 256 threads cover 256 bins
    __syncthreads();

    const uint4* row4 = (const uint4*)(binb + (size_t)b * N_DB);  // 6250 uint4

    // ---- sample pass: every 8th uint4 (781 of 6250) -> 256-bin histogram ----
    for (int k = tid; k < 781; k += 256) {
        uint4 w = row4[k * 8];
        unsigned ws[4] = {w.x, w.y, w.z, w.w};
        #pragma unroll
        for (int q = 0; q < 4; q++)
            #pragma unroll
            for (int e = 0; e < 4; e++)
                atomicAdd(&hist[(ws[q] >> (8 * e)) & 255u], 1);
    }
    __syncthreads();
    if (tid == 0) {
        int cum = 0, t = 255;
        for (int i = 0; i < 256; i++) {
            cum += hist[i];
            if (cum >= STGT) { t = i; break; }
        }
        s_thr = t;
    }
    __syncthreads();

    // ---- verify + collect pass (retry loop guarantees correctness) ----
    int cnt = 0;
    for (int attempt = 0; attempt < 6; attempt++) {
        if (tid == 0) { s_cnt = 0; s_nle = 0; }
        __syncthreads();
        int thr = s_thr;
        int thrc = thr + 2 > 255 ? 255 : thr + 2;        // +2: floor boundary + bf16 error
        int nle = 0;
        for (int v = tid; v < 6250; v += 256) {
            uint4 w = row4[v];
            unsigned ws[4] = {w.x, w.y, w.z, w.w};
            #pragma unroll
            for (int q = 0; q < 4; q++)
                #pragma unroll
                for (int e = 0; e < 4; e++) {
                    int by = (int)((ws[q] >> (8 * e)) & 255u);
                    nle += (by <= thr);
                    if (by <= thrc) {
                        int pos = atomicAdd(&s_cnt, 1);
                        if (pos < CMAX) cand_n[pos] = v * 16 + q * 4 + e;
                    }
                }
        }
        #pragma unroll
        for (int off = 32; off; off >>= 1) nle += __shfl_xor(nle, off, 64);
        if (lane == 0) atomicAdd(&s_nle, nle);
        __syncthreads();
        cnt = s_cnt;
        if (s_nle >= K_NN && cnt <= CMAX) break;         // >=100 bytes <= thr  =>  set is safe
        if (tid == 0) { if (s_nle < K_NN) s_thr += 3; else s_thr -= 2; }
        __syncthreads();
    }
    if (cnt > CMAX) cnt = CMAX;

    // ---- exact f32 refine of candidates ----
    float xx = x2[b];
    for (int c = tid; c < cnt; c += 256) {
        int n = cand_n[c];
        const float4* dr = (const float4*)(db_X + (size_t)n * D_F);
        float dot = 0.f;
        #pragma unroll
        for (int k = 0; k < 16; k++) {
            float4 w = dr[k];
            dot += xrow[k * 4 + 0] * w.x + xrow[k * 4 + 1] * w.y
                 + xrow[k * 4 + 2] * w.z + xrow[k * 4 + 3] * w.w;
        }
        cand_d[c] = (xx - 2.0f * dot + d2[n]) * (1.0f / D_F);
    }
    __syncthreads();

    // ---- exact rank (total order via (dist, idx)) -> top-K set ----
    for (int c = tid; c < cnt; c += 256) {
        float dc = cand_d[c]; int nc = cand_n[c];
        int rank = 0;
        for (int j = 0; j < cnt; j++) {
            float dj = cand_d[j];
            rank += (dj < dc) || (dj == dc && cand_n[j] < nc);
        }
        if (rank < K_NN) idx[(size_t)b * K_NN + rank] = nc;
    }
}

// ---------------- per-row regression + loss ----------------
__global__ __launch_bounds__(256) void k_regress(
    const float* __restrict__ input, const float* __restrict__ target,
    const float* __restrict__ db_X, const float* __restrict__ db_y,
    const int* __restrict__ idx, float* __restrict__ out) {
    int b = blockIdx.x, tid = threadIdx.x;
    __shared__ float A[K_NN * AST];          // [k][p], col0 = 1, cols 65..67 = 0
    __shared__ float M[65 * AST];
    __shared__ float v[65], xa[68], yv[K_NN];
    __shared__ int nbr[K_NN];

    if (tid < K_NN) {
        int n = idx[(size_t)b * K_NN + tid];
        nbr[tid] = n;
        yv[tid] = db_y[n];
    }
    if (tid < 64) xa[1 + tid] = input[(size_t)b * D_F + tid];
    if (tid == 0) { xa[0] = 1.f; xa[65] = xa[66] = xa[67] = 0.f; }
    __syncthreads();

    for (int f = tid; f < K_NN * AST; f += 256) {
        int k = f / AST, c = f - k * AST;
        float val = 0.f;
        if (c == 0) val = 1.f;
        else if (c <= 64) val = db_X[(size_t)nbr[k] * D_F + (c - 1)];
        A[f] = val;
    }
    __syncthreads();

    // AtA via 4x4 register tiles
    for (int t = tid; t < 289; t += 256) {
        int ti = t / 17, tj = t % 17;
        int p0 = ti * 4, q0 = tj * 4;
        float acc[4][4];
        #pragma unroll
        for (int ii = 0; ii < 4; ii++)
            #pragma unroll
            for (int jj = 0; jj < 4; jj++) acc[ii][jj] = 0.f;
        for (int k = 0; k < K_NN; k++) {
            float4 ap = *(const float4*)(&A[k * AST + p0]);
            float4 aq = *(const float4*)(&A[k * AST + q0]);
            float app[4] = {ap.x, ap.y, ap.z, ap.w};
            float aqq[4] = {aq.x, aq.y, aq.z, aq.w};
            #pragma unroll
            for (int ii = 0; ii < 4; ii++)
                #pragma unroll
                for (int jj = 0; jj < 4; jj++) acc[ii][jj] += app[ii] * aqq[jj];
        }
        #pragma unroll
        for (int ii = 0; ii < 4; ii++)
            #pragma unroll
            for (int jj = 0; jj < 4; jj++) {
                int p = p0 + ii, q = q0 + jj;
                if (p < 65 && q < 65)
                    M[p * AST + q] = acc[ii][jj] + (p == q ? JITTER : 0.f);
            }
    }
    for (int p = tid; p < 65; p += 256) {
        float s = 0.f;
        for (int k = 0; k < K_NN; k++) s += A[k * AST + p] * yv[k];
        v[p] = s;
    }
    __syncthreads();

    // Gaussian elimination (SPD, no pivot)
    for (int j = 0; j < 65; j++) {
        float inv = 1.0f / M[j * AST + j];
        int kcol = j + 1 + (tid & 63);
        int rbase = j + 1 + (tid >> 6);
        if (kcol <= 64) {
            float mjk = M[j * AST + kcol] * inv;
            for (int i = rbase; i <= 64; i += 4)
                M[i * AST + kcol] -= M[i * AST + j] * mjk;
        }
        __syncthreads();
    }
    for (int j = 0; j < 65; j++) {
        float inv = 1.0f / M[j * AST + j];
        float vj = v[j];
        for (int i = j + 1 + tid; i < 65; i += 256) v[i] -= M[i * AST + j] * inv * vj;
        __syncthreads();
    }
    for (int j = 64; j >= 0; j--) {
        if (tid == 0) v[j] /= M[j * AST + j];
        __syncthreads();
        float xj = v[j];
        for (int i = tid; i < j; i += 256) v[i] -= M[i * AST + j] * xj;
        __syncthreads();
    }

    if (tid == 0) {
        float pred = 0.f;
        for (int q = 0; q <= 64; q++) pred += xa[q] * v[q];
        float e = pred - target[b];
        atomicAdd(out, e * e * (1.0f / B_Q));
    }
}

extern "C" void kernel_launch(void* const* d_in, const int* in_sizes, int n_in,
                              void* d_out, int out_size, void* d_ws, size_t ws_size,
                              hipStream_t stream) {
    const float* input  = (const float*)d_in[0];
    const float* target = (const float*)d_in[1];
    const float* db_X   = (const float*)d_in[2];
    const float* db_y   = (const float*)d_in[3];
    float* out = (float*)d_out;

    char* ws = (char*)d_ws;
    size_t off = 0;
    auto alloc = [&](size_t bytes) {
        size_t o = off;
        off += (bytes + 255) & ~(size_t)255;
        return o;
    };
    float* d2   = (float*)(ws + alloc((size_t)N_DB * 4));
    float* x2   = (float*)(ws + alloc((size_t)B_Q * 4));
    int*   idx  = (int*)(ws + alloc((size_t)B_Q * K_NN * 4));
    unsigned char* binb = (unsigned char*)(ws + alloc((size_t)B_Q * N_DB));

    hipMemsetAsync(d_out, 0, sizeof(float) * out_size, stream);

    {
        int waves = N_DB + B_Q;
        k_sqnorm<<<(waves + 3) / 4, 256, 0, stream>>>(db_X, input, d2, x2);
    }
    {
        dim3 g((N_DB + 127) / 128, B_Q / 128);
        k_gemm_bin<<<g, 256, 0, stream>>>(input, db_X, x2, d2, binb);
    }
    k_select<<<B_Q, 256, 0, stream>>>(binb, input, db_X, x2, d2, idx);
    k_regress<<<B_Q, 256, 0, stream>>>(input, target, db_X, db_y, idx, out);
}